// Round 1
// baseline (6633.494 us; speedup 1.0000x reference)
//
#include <hip/hip_runtime.h>
#include <hip/hip_bf16.h>
#include <math.h>

// Problem constants (fixed by the reference)
#define BB 4
#define TT 2048
#define CC 256
#define HH 4
#define LL 2
#define VV 1024
#define HS 64

// ---------------------------------------------------------------------------
// Embedding gather: x[row, :] = wte[tok[row], :]
// ---------------------------------------------------------------------------
__global__ void embed_kernel(const int* __restrict__ tok,
                             const float* __restrict__ wte,
                             float* __restrict__ x) {
    int row = blockIdx.x;       // 0 .. B*T-1
    int tid = threadIdx.x;      // 0 .. 255 == C
    int tk = tok[row];
    x[(size_t)row * CC + tid] = wte[(size_t)tk * CC + tid];
}

// ---------------------------------------------------------------------------
// LayerNorm over C=256, one block (256 threads) per row.
// var = E[x^2] - mu^2 (matches jnp.var ddof=0), eps inside sqrt.
// ---------------------------------------------------------------------------
__global__ void ln_kernel(const float* __restrict__ x,
                          const float* __restrict__ g,
                          const float* __restrict__ b,
                          float* __restrict__ out) {
    int row = blockIdx.x;
    int tid = threadIdx.x;
    __shared__ float r1[256];
    __shared__ float r2[256];
    float v = x[(size_t)row * CC + tid];
    r1[tid] = v;
    r2[tid] = v * v;
    __syncthreads();
    for (int off = 128; off > 0; off >>= 1) {
        if (tid < off) { r1[tid] += r1[tid + off]; r2[tid] += r2[tid + off]; }
        __syncthreads();
    }
    float mean = r1[0] * (1.0f / CC);
    float var  = r2[0] * (1.0f / CC) - mean * mean;
    float rs = rsqrtf(var + 1e-5f);
    out[(size_t)row * CC + tid] = (v - mean) * rs * g[tid] + b[tid];
}

// ---------------------------------------------------------------------------
// fp32 tiled GEMM: out[M,N] = A[M,K] @ W[N,K]^T (+ bias) (+gelu) (+=out)
// 64x64 tile, BK=16, 256 threads, 4x4 per thread.
// ---------------------------------------------------------------------------
__device__ __forceinline__ float gelu_f(float v) {
    return 0.5f * v * (1.0f + tanhf(0.7978845608028654f * (v + 0.044715f * v * v * v)));
}

template<int ADD, int DOGELU>
__global__ void gemm_kernel(const float* __restrict__ A,
                            const float* __restrict__ W,
                            const float* __restrict__ bias,
                            float* __restrict__ out,
                            int M, int N, int K) {
    // Padded to 68 -> <=2-way LDS bank aliasing (free on CDNA4)
    __shared__ float As[16][68];
    __shared__ float Bs[16][68];
    int row0 = blockIdx.y * 64;
    int col0 = blockIdx.x * 64;
    int tid = threadIdx.x;
    int tx = tid & 15, ty = tid >> 4;
    int lm = tid >> 2;            // 0..63 tile row
    int lk = (tid & 3) * 4;       // 0,4,8,12 k-offset
    float acc[4][4] = {};
    const float* Ap = A + (size_t)(row0 + lm) * K + lk;
    const float* Wp = W + (size_t)(col0 + lm) * K + lk;
    for (int k0 = 0; k0 < K; k0 += 16) {
        float4 av = *(const float4*)(Ap + k0);
        float4 wv = *(const float4*)(Wp + k0);
        As[lk + 0][lm] = av.x; As[lk + 1][lm] = av.y;
        As[lk + 2][lm] = av.z; As[lk + 3][lm] = av.w;
        Bs[lk + 0][lm] = wv.x; Bs[lk + 1][lm] = wv.y;
        Bs[lk + 2][lm] = wv.z; Bs[lk + 3][lm] = wv.w;
        __syncthreads();
#pragma unroll
        for (int kk = 0; kk < 16; kk++) {
            float a[4], bv[4];
#pragma unroll
            for (int i = 0; i < 4; i++) a[i] = As[kk][ty * 4 + i];
#pragma unroll
            for (int j = 0; j < 4; j++) bv[j] = Bs[kk][tx * 4 + j];
#pragma unroll
            for (int i = 0; i < 4; i++)
#pragma unroll
                for (int j = 0; j < 4; j++)
                    acc[i][j] = fmaf(a[i], bv[j], acc[i][j]);
        }
        __syncthreads();
    }
#pragma unroll
    for (int i = 0; i < 4; i++) {
        int r = row0 + ty * 4 + i;
#pragma unroll
        for (int j = 0; j < 4; j++) {
            int c = col0 + tx * 4 + j;
            float v = acc[i][j] + (bias ? bias[c] : 0.0f);
            if (DOGELU) v = gelu_f(v);
            size_t o = (size_t)r * N + c;
            if (ADD) out[o] += v; else out[o] = v;
        }
    }
}

// ---------------------------------------------------------------------------
// Relative-position causal attention, one block (256 threads) per (b,h,t).
// score[s] = 0.125 * q.k[s] + q.embk[t-s]   (s <= t)
// y[d] = (1/sum) * sum_s p[s] * (v[s,d] + embv[t-s,d])
// ---------------------------------------------------------------------------
__global__ void attn_kernel(const float* __restrict__ qkv,
                            const float* __restrict__ embk,
                            const float* __restrict__ embv,
                            float* __restrict__ y) {
    int idx = blockIdx.x;
    int t = idx & (TT - 1);
    int h = (idx >> 11) & (HH - 1);
    int b = idx >> 13;
    int tid = threadIdx.x;

    __shared__ float qs[HS];
    __shared__ float sc[TT];      // 8 KB of scores/probs
    __shared__ float red[256];

    const float* qrow = qkv + ((size_t)(b * TT + t)) * (3 * CC) + h * HS;
    if (tid < HS) qs[tid] = qrow[tid];
    __syncthreads();

    // pass 1: scores + max
    float lmax = -1e30f;
    for (int s = tid; s <= t; s += 256) {
        const float* krow = qkv + ((size_t)(b * TT + s)) * (3 * CC) + CC + h * HS;
        const float* ek = embk + (size_t)(t - s) * HS;
        float a = 0.0f, r = 0.0f;
#pragma unroll 8
        for (int d = 0; d < HS; d++) {
            a = fmaf(qs[d], krow[d], a);
            r = fmaf(qs[d], ek[d], r);
        }
        float v = 0.125f * a + r;
        sc[s] = v;
        lmax = fmaxf(lmax, v);
    }
    red[tid] = lmax;
    __syncthreads();
    for (int off = 128; off > 0; off >>= 1) {
        if (tid < off) red[tid] = fmaxf(red[tid], red[tid + off]);
        __syncthreads();
    }
    float mx = red[0];
    __syncthreads();

    // exp + sum
    float lsum = 0.0f;
    for (int s = tid; s <= t; s += 256) {
        float p = __expf(sc[s] - mx);
        sc[s] = p;
        lsum += p;
    }
    red[tid] = lsum;
    __syncthreads();
    for (int off = 128; off > 0; off >>= 1) {
        if (tid < off) red[tid] += red[tid + off];
        __syncthreads();
    }
    float inv = 1.0f / red[0];
    __syncthreads();

    // pass 2: weighted V + embv
    int d = tid & (HS - 1);
    int g = tid >> 6;             // 0..3
    float acc = 0.0f;
    for (int s = g; s <= t; s += 4) {
        const float* vrow = qkv + ((size_t)(b * TT + s)) * (3 * CC) + 2 * CC + h * HS;
        const float* ev = embv + (size_t)(t - s) * HS;
        acc = fmaf(sc[s], vrow[d] + ev[d], acc);
    }
    red[g * HS + d] = acc;
    __syncthreads();
    if (g == 0) {
        float r2 = red[d] + red[HS + d] + red[2 * HS + d] + red[3 * HS + d];
        y[((size_t)(b * TT + t)) * CC + h * HS + d] = r2 * inv;
    }
}

// ---------------------------------------------------------------------------
extern "C" void kernel_launch(void* const* d_in, const int* in_sizes, int n_in,
                              void* d_out, int out_size, void* d_ws, size_t ws_size,
                              hipStream_t stream) {
    const int*   tokens  = (const int*)d_in[0];
    const float* wte     = (const float*)d_in[1];
    const float* ln1_g   = (const float*)d_in[2];
    const float* ln1_b   = (const float*)d_in[3];
    const float* attn_w  = (const float*)d_in[4];
    const float* attn_b  = (const float*)d_in[5];
    const float* proj_w  = (const float*)d_in[6];
    const float* proj_b  = (const float*)d_in[7];
    const float* embk    = (const float*)d_in[8];
    const float* embv    = (const float*)d_in[9];
    const float* ln2_g   = (const float*)d_in[10];
    const float* ln2_b   = (const float*)d_in[11];
    const float* fc_w    = (const float*)d_in[12];
    const float* fc_b    = (const float*)d_in[13];
    const float* mproj_w = (const float*)d_in[14];
    const float* mproj_b = (const float*)d_in[15];
    const float* lnf_g   = (const float*)d_in[16];
    const float* lnf_b   = (const float*)d_in[17];
    const float* head_w  = (const float*)d_in[18];
    float* out = (float*)d_out;

    const int M = BB * TT;  // 8192

    // workspace layout (floats): x, h, qkv, y  = 48 MB total
    float* x   = (float*)d_ws;
    float* h   = x + (size_t)M * CC;
    float* qkv = h + (size_t)M * CC;
    float* y   = qkv + (size_t)M * 3 * CC;
    // fc activation [8192, 1024] exactly fits d_out; reused as scratch,
    // overwritten at the end by the head GEMM.
    float* fc  = out;

    dim3 blk(256);

    embed_kernel<<<dim3(M), blk, 0, stream>>>(tokens, wte, x);

    for (int l = 0; l < LL; l++) {
        ln_kernel<<<dim3(M), blk, 0, stream>>>(x, ln1_g + l * CC, ln1_b + l * CC, h);
        gemm_kernel<0, 0><<<dim3(12, 128), blk, 0, stream>>>(
            h, attn_w + (size_t)l * 3 * CC * CC, attn_b + (size_t)l * 3 * CC,
            qkv, M, 3 * CC, CC);
        attn_kernel<<<dim3(BB * HH * TT), blk, 0, stream>>>(
            qkv, embk + (size_t)l * TT * HS, embv + (size_t)l * TT * HS, y);
        gemm_kernel<1, 0><<<dim3(4, 128), blk, 0, stream>>>(
            y, proj_w + (size_t)l * CC * CC, proj_b + (size_t)l * CC,
            x, M, CC, CC);
        ln_kernel<<<dim3(M), blk, 0, stream>>>(x, ln2_g + l * CC, ln2_b + l * CC, h);
        gemm_kernel<0, 1><<<dim3(16, 128), blk, 0, stream>>>(
            h, fc_w + (size_t)l * 4 * CC * CC, fc_b + (size_t)l * 4 * CC,
            fc, M, 4 * CC, CC);
        gemm_kernel<1, 0><<<dim3(4, 128), blk, 0, stream>>>(
            fc, mproj_w + (size_t)l * CC * 4 * CC, mproj_b + (size_t)l * CC,
            x, M, CC, 4 * CC);
    }

    ln_kernel<<<dim3(M), blk, 0, stream>>>(x, lnf_g, lnf_b, h);
    gemm_kernel<0, 0><<<dim3(16, 128), blk, 0, stream>>>(
        h, head_w, nullptr, out, M, VV, CC);
}

// Round 2
// 990.810 us; speedup vs baseline: 6.6950x; 6.6950x over previous
//
#include <hip/hip_runtime.h>
#include <hip/hip_bf16.h>
#include <math.h>

#define BB 4
#define TT 2048
#define CC 256
#define HH 4
#define LL 2
#define VV 1024
#define HS 64

typedef __attribute__((ext_vector_type(8))) __bf16 bf16x8;
typedef __attribute__((ext_vector_type(4))) float f32x4;

__device__ __forceinline__ ushort f2bf(float f) {
    __hip_bfloat16 h = __float2bfloat16(f);
    return *reinterpret_cast<ushort*>(&h);
}

// ---------------------------------------------------------------------------
__global__ void embed_kernel(const int* __restrict__ tok,
                             const float* __restrict__ wte,
                             float* __restrict__ x) {
    int row = blockIdx.x;
    int tid = threadIdx.x;
    int tk = tok[row];
    x[(size_t)row * CC + tid] = wte[(size_t)tk * CC + tid];
}

// ---------------------------------------------------------------------------
__global__ void ln_kernel(const float* __restrict__ x,
                          const float* __restrict__ g,
                          const float* __restrict__ b,
                          float* __restrict__ out) {
    int row = blockIdx.x;
    int tid = threadIdx.x;
    __shared__ float r1[256];
    __shared__ float r2[256];
    float v = x[(size_t)row * CC + tid];
    r1[tid] = v;
    r2[tid] = v * v;
    __syncthreads();
    for (int off = 128; off > 0; off >>= 1) {
        if (tid < off) { r1[tid] += r1[tid + off]; r2[tid] += r2[tid + off]; }
        __syncthreads();
    }
    float mean = r1[0] * (1.0f / CC);
    float var  = r2[0] * (1.0f / CC) - mean * mean;
    float rs = rsqrtf(var + 1e-5f);
    out[(size_t)row * CC + tid] = (v - mean) * rs * g[tid] + b[tid];
}

// ---------------------------------------------------------------------------
__device__ __forceinline__ float gelu_f(float v) {
    return 0.5f * v * (1.0f + tanhf(0.7978845608028654f * (v + 0.044715f * v * v * v)));
}

// MODE: 0=store, 1=add-accumulate, 2=gelu+store, 3=qkv->bf16 split epilogue
template<int MODE>
__global__ void gemm_kernel(const float* __restrict__ A,
                            const float* __restrict__ W,
                            const float* __restrict__ bias,
                            float* __restrict__ out,
                            int M, int N, int K,
                            ushort* __restrict__ qb,
                            ushort* __restrict__ kb,
                            ushort* __restrict__ vtb) {
    __shared__ float As[16][68];
    __shared__ float Bs[16][68];
    int row0 = blockIdx.y * 64;
    int col0 = blockIdx.x * 64;
    int tid = threadIdx.x;
    int tx = tid & 15, ty = tid >> 4;
    int lm = tid >> 2;
    int lk = (tid & 3) * 4;
    float acc[4][4] = {};
    const float* Ap = A + (size_t)(row0 + lm) * K + lk;
    const float* Wp = W + (size_t)(col0 + lm) * K + lk;
    for (int k0 = 0; k0 < K; k0 += 16) {
        float4 av = *(const float4*)(Ap + k0);
        float4 wv = *(const float4*)(Wp + k0);
        As[lk + 0][lm] = av.x; As[lk + 1][lm] = av.y;
        As[lk + 2][lm] = av.z; As[lk + 3][lm] = av.w;
        Bs[lk + 0][lm] = wv.x; Bs[lk + 1][lm] = wv.y;
        Bs[lk + 2][lm] = wv.z; Bs[lk + 3][lm] = wv.w;
        __syncthreads();
#pragma unroll
        for (int kk = 0; kk < 16; kk++) {
            float a[4], bv[4];
#pragma unroll
            for (int i = 0; i < 4; i++) a[i] = As[kk][ty * 4 + i];
#pragma unroll
            for (int j = 0; j < 4; j++) bv[j] = Bs[kk][tx * 4 + j];
#pragma unroll
            for (int i = 0; i < 4; i++)
#pragma unroll
                for (int j = 0; j < 4; j++)
                    acc[i][j] = fmaf(a[i], bv[j], acc[i][j]);
        }
        __syncthreads();
    }
#pragma unroll
    for (int i = 0; i < 4; i++) {
        int r = row0 + ty * 4 + i;
#pragma unroll
        for (int j = 0; j < 4; j++) {
            int c = col0 + tx * 4 + j;
            float v = acc[i][j] + (bias ? bias[c] : 0.0f);
            if (MODE == 2) v = gelu_f(v);
            if (MODE == 3) {
                int bb2 = r >> 11, t = r & 2047;
                int which = c >> 8, hh = (c >> 6) & 3, dd = c & 63;
                size_t bh = (size_t)(bb2 * 4 + hh);
                if (which == 0)      qb[(bh * 2048 + t) * 64 + dd] = f2bf(v);
                else if (which == 1) kb[(bh * 2048 + t) * 64 + dd] = f2bf(v * 0.125f);
                else                 vtb[(bh * 64 + dd) * 2048 + t] = f2bf(v);
            } else {
                size_t o = (size_t)r * N + c;
                if (MODE == 1) out[o] += v; else out[o] = v;
            }
        }
    }
}

// ---------------------------------------------------------------------------
// embk/embv -> padded bf16 copies. ekp[64+o][d] = embk[o][d] (zeros outside),
// evtp[d][64+o] = embv[o][d] (zeros outside). Rows span o in [-64, 2112).
// ---------------------------------------------------------------------------
#define EPAD 2176
__global__ void emb_bf_kernel(const float* __restrict__ ek,
                              const float* __restrict__ ev,
                              ushort* __restrict__ ekp,
                              ushort* __restrict__ evtp) {
    int i = blockIdx.x * 256 + threadIdx.x;   // over EPAD*64
    int rp = i >> 6, d = i & 63;
    int o = rp - 64;
    bool in = (o >= 0 && o < TT);
    float kv = in ? ek[(size_t)o * 64 + d] : 0.0f;
    float vv = in ? ev[(size_t)o * 64 + d] : 0.0f;
    ekp[(size_t)rp * 64 + d] = f2bf(kv);
    evtp[(size_t)d * EPAD + rp] = f2bf(vv);
}

// ---------------------------------------------------------------------------
// Fused flash attention with relative position, bf16 MFMA.
// One 64-thread wave per block; wave owns 16 query rows of one (b,h).
// S[t,s] = q.(0.125 k[s]) + q.embk[t-s];  y = P.v + P'.embv (band form).
// ---------------------------------------------------------------------------
#define MFMA16(a, b, c) __builtin_amdgcn_mfma_f32_16x16x32_bf16((a), (b), (c), 0, 0, 0)

__global__ __launch_bounds__(64, 3) void flash_kernel(
        const ushort* __restrict__ qb,    // [16][2048][64]
        const ushort* __restrict__ kb,    // [16][2048][64] (pre-scaled 0.125)
        const ushort* __restrict__ vtb,   // [16][64][2048]
        const ushort* __restrict__ ekp,   // [EPAD][64], row 64+o
        const ushort* __restrict__ evtp,  // [64][EPAD], col 64+o
        float* __restrict__ y) {          // [B,T,C]
    __shared__ float  Rl[16][84];         // R band tile (f32)
    __shared__ ushort Pl[16][72];         // P (bf16), cols 0..63
    __shared__ ushort Ppl[16][104];       // skewed P' (bf16), cols 0..95

    int bid = blockIdx.x;
    int bh = bid & 15;                    // b*4 + h
    int wt = 127 - (bid >> 4);            // heavy tiles dispatched first
    int t0 = wt * 16;
    int lane = threadIdx.x;
    int lo = lane & 15, hi = lane >> 4;

    // Q fragments (A operand): row = lane%16, k = (lane/16)*8 + i
    const ushort* qbase = qb + ((size_t)bh * 2048 + t0) * 64;
    bf16x8 qf0 = *(const bf16x8*)(qbase + (size_t)lo * 64 + hi * 8);
    bf16x8 qf1 = *(const bf16x8*)(qbase + (size_t)lo * 64 + 32 + hi * 8);

    // zero P' once: per-row valid window [r+1, r+64] is iteration-invariant
    {
        uint* pz = reinterpret_cast<uint*>(&Ppl[0][0]);
        for (int i = lane; i < 16 * 104 / 2; i += 64) pz[i] = 0;
    }

    float m[4], l[4];
    f32x4 O[4] = {};
#pragma unroll
    for (int j = 0; j < 4; j++) { m[j] = -1e30f; l[j] = 0.0f; }

    const ushort* vbase = vtb + (size_t)bh * 64 * 2048;
    int NS = (t0 >> 6) + 1;

    for (int it = 0; it < NS; ++it) {
        int s0 = it * 64;
        int ob = t0 - s0 - 64;            // band base offset (multiple of 16)

        // ---- S = Q K^T (k pre-scaled) ----
        f32x4 sacc[4] = {};
        const ushort* kbb = kb + ((size_t)bh * 2048 + s0) * 64;
#pragma unroll
        for (int n = 0; n < 4; ++n) {
            bf16x8 b0 = *(const bf16x8*)(kbb + (size_t)(n * 16 + lo) * 64 + hi * 8);
            bf16x8 b1 = *(const bf16x8*)(kbb + (size_t)(n * 16 + lo) * 64 + 32 + hi * 8);
            sacc[n] = MFMA16(qf0, b0, sacc[n]);
            sacc[n] = MFMA16(qf1, b1, sacc[n]);
        }
        // ---- R = Q ek_band^T, write to LDS ----
#pragma unroll
        for (int n = 0; n < 5; ++n) {
            f32x4 r = {};
            const ushort* ekr = ekp + (size_t)(64 + ob + n * 16 + lo) * 64;
            bf16x8 e0 = *(const bf16x8*)(ekr + hi * 8);
            bf16x8 e1 = *(const bf16x8*)(ekr + 32 + hi * 8);
            r = MFMA16(qf0, e0, r);
            r = MFMA16(qf1, e1, r);
#pragma unroll
            for (int j = 0; j < 4; ++j) Rl[hi * 4 + j][n * 16 + lo] = r[j];
        }
        // ---- combine, mask, online softmax ----
        float sv[4][4];
        float mrow[4] = {-1e30f, -1e30f, -1e30f, -1e30f};
#pragma unroll
        for (int n = 0; n < 4; ++n) {
            int sl = n * 16 + lo;
#pragma unroll
            for (int j = 0; j < 4; ++j) {
                int r_ = hi * 4 + j;
                float v = sacc[n][j] + Rl[r_][r_ - sl + 64];
                v = (s0 + sl <= t0 + r_) ? v : -1e30f;
                sv[n][j] = v;
                mrow[j] = fmaxf(mrow[j], v);
            }
        }
#pragma unroll
        for (int msk = 1; msk < 16; msk <<= 1) {
#pragma unroll
            for (int j = 0; j < 4; ++j)
                mrow[j] = fmaxf(mrow[j], __shfl_xor(mrow[j], msk));
        }
        float alpha[4];
#pragma unroll
        for (int j = 0; j < 4; ++j) {
            float mn = fmaxf(m[j], mrow[j]);
            alpha[j] = __expf(m[j] - mn);
            m[j] = mn;
        }
        float rs[4] = {0, 0, 0, 0};
#pragma unroll
        for (int n = 0; n < 4; ++n) {
            int sl = n * 16 + lo;
#pragma unroll
            for (int j = 0; j < 4; ++j) {
                int r_ = hi * 4 + j;
                float p = __expf(sv[n][j] - m[j]);
                rs[j] += p;
                ushort pu = f2bf(p);
                Pl[r_][sl] = pu;
                Ppl[r_][r_ - sl + 64] = pu;
            }
        }
#pragma unroll
        for (int msk = 1; msk < 16; msk <<= 1) {
#pragma unroll
            for (int j = 0; j < 4; ++j) rs[j] += __shfl_xor(rs[j], msk);
        }
#pragma unroll
        for (int j = 0; j < 4; ++j) l[j] = l[j] * alpha[j] + rs[j];
#pragma unroll
        for (int n = 0; n < 4; ++n)
#pragma unroll
            for (int j = 0; j < 4; ++j) O[n][j] *= alpha[j];

        // ---- O += P V + P' embv_band ----
#pragma unroll
        for (int n = 0; n < 4; ++n) {
            const ushort* vr = vbase + (size_t)(n * 16 + lo) * 2048;
            const ushort* er = evtp + (size_t)(n * 16 + lo) * EPAD + 64 + ob;
#pragma unroll
            for (int kc = 0; kc < 2; ++kc) {
                bf16x8 a = *(const bf16x8*)(&Pl[lo][kc * 32 + hi * 8]);
                bf16x8 b = *(const bf16x8*)(vr + s0 + kc * 32 + hi * 8);
                O[n] = MFMA16(a, b, O[n]);
            }
#pragma unroll
            for (int kc = 0; kc < 3; ++kc) {
                bf16x8 a = *(const bf16x8*)(&Ppl[lo][kc * 32 + hi * 8]);
                bf16x8 b = *(const bf16x8*)(er + kc * 32 + hi * 8);
                O[n] = MFMA16(a, b, O[n]);
            }
        }
    }
    // ---- epilogue: y[b, t, h*64+d] = O / l ----
    int b_ = bh >> 2, h_ = bh & 3;
#pragma unroll
    for (int n = 0; n < 4; ++n) {
#pragma unroll
        for (int j = 0; j < 4; ++j) {
            int r_ = hi * 4 + j;
            y[((size_t)(b_ * 2048 + t0 + r_)) * 256 + h_ * 64 + n * 16 + lo] =
                O[n][j] / l[j];
        }
    }
}

// ---------------------------------------------------------------------------
extern "C" void kernel_launch(void* const* d_in, const int* in_sizes, int n_in,
                              void* d_out, int out_size, void* d_ws, size_t ws_size,
                              hipStream_t stream) {
    const int*   tokens  = (const int*)d_in[0];
    const float* wte     = (const float*)d_in[1];
    const float* ln1_g   = (const float*)d_in[2];
    const float* ln1_b   = (const float*)d_in[3];
    const float* attn_w  = (const float*)d_in[4];
    const float* attn_b  = (const float*)d_in[5];
    const float* proj_w  = (const float*)d_in[6];
    const float* proj_b  = (const float*)d_in[7];
    const float* embk    = (const float*)d_in[8];
    const float* embv    = (const float*)d_in[9];
    const float* ln2_g   = (const float*)d_in[10];
    const float* ln2_b   = (const float*)d_in[11];
    const float* fc_w    = (const float*)d_in[12];
    const float* fc_b    = (const float*)d_in[13];
    const float* mproj_w = (const float*)d_in[14];
    const float* mproj_b = (const float*)d_in[15];
    const float* lnf_g   = (const float*)d_in[16];
    const float* lnf_b   = (const float*)d_in[17];
    const float* head_w  = (const float*)d_in[18];
    float* out = (float*)d_out;

    const int M = BB * TT;  // 8192

    // ws: x(8MB) h(8MB) y(8MB) + bf16 block (~12.6MB) = ~37MB
    float* x = (float*)d_ws;
    float* h = x + (size_t)M * CC;
    float* y = h + (size_t)M * CC;
    ushort* qb   = (ushort*)(y + (size_t)M * CC);
    ushort* kbf  = qb  + (size_t)16 * 2048 * 64;
    ushort* vtb  = kbf + (size_t)16 * 2048 * 64;
    ushort* ekp  = vtb + (size_t)16 * 2048 * 64;
    ushort* evtp = ekp + (size_t)EPAD * 64;
    float* fc = out;  // d_out reused as fc scratch, overwritten by head GEMM

    dim3 blk(256);

    embed_kernel<<<dim3(M), blk, 0, stream>>>(tokens, wte, x);

    for (int l = 0; l < LL; l++) {
        ln_kernel<<<dim3(M), blk, 0, stream>>>(x, ln1_g + l * CC, ln1_b + l * CC, h);
        gemm_kernel<3><<<dim3(12, 128), blk, 0, stream>>>(
            h, attn_w + (size_t)l * 3 * CC * CC, attn_b + (size_t)l * 3 * CC,
            nullptr, M, 3 * CC, CC, qb, kbf, vtb);
        emb_bf_kernel<<<dim3(EPAD * 64 / 256), blk, 0, stream>>>(
            embk + (size_t)l * TT * HS, embv + (size_t)l * TT * HS, ekp, evtp);
        flash_kernel<<<dim3(2048), dim3(64), 0, stream>>>(qb, kbf, vtb, ekp, evtp, y);
        gemm_kernel<1><<<dim3(4, 128), blk, 0, stream>>>(
            y, proj_w + (size_t)l * CC * CC, proj_b + (size_t)l * CC,
            x, M, CC, CC, nullptr, nullptr, nullptr);
        ln_kernel<<<dim3(M), blk, 0, stream>>>(x, ln2_g + l * CC, ln2_b + l * CC, h);
        gemm_kernel<2><<<dim3(16, 128), blk, 0, stream>>>(
            h, fc_w + (size_t)l * 4 * CC * CC, fc_b + (size_t)l * 4 * CC,
            fc, M, 4 * CC, CC, nullptr, nullptr, nullptr);
        gemm_kernel<1><<<dim3(4, 128), blk, 0, stream>>>(
            fc, mproj_w + (size_t)l * CC * 4 * CC, mproj_b + (size_t)l * CC,
            x, M, CC, 4 * CC, nullptr, nullptr, nullptr);
    }

    ln_kernel<<<dim3(M), blk, 0, stream>>>(x, lnf_g, lnf_b, h);
    gemm_kernel<0><<<dim3(16, 128), blk, 0, stream>>>(
        h, head_w, nullptr, out, M, VV, CC, nullptr, nullptr, nullptr);
}

// Round 3
// 556.058 us; speedup vs baseline: 11.9295x; 1.7818x over previous
//
#include <hip/hip_runtime.h>
#include <hip/hip_bf16.h>
#include <math.h>

#define BB 4
#define TT 2048
#define CC 256
#define HH 4
#define LL 2
#define VV 1024
#define HS 64
#define EPAD 2176

typedef __attribute__((ext_vector_type(8))) __bf16 bf16x8;
typedef __attribute__((ext_vector_type(4))) float f32x4;

#define MFMA16(a, b, c) __builtin_amdgcn_mfma_f32_16x16x32_bf16((a), (b), (c), 0, 0, 0)

__device__ __forceinline__ ushort f2bf(float f) {
    __hip_bfloat16 h = __float2bfloat16(f);
    return *reinterpret_cast<ushort*>(&h);
}

__device__ __forceinline__ void gload16(const void* g, void* l) {
    __builtin_amdgcn_global_load_lds(
        (const __attribute__((address_space(1))) void*)g,
        (__attribute__((address_space(3))) void*)l, 16, 0, 0);
}

__device__ __forceinline__ float gelu_f(float v) {
    return 0.5f * v * (1.0f + tanhf(0.7978845608028654f * (v + 0.044715f * v * v * v)));
}

// ---------------------------------------------------------------------------
__global__ void embed_kernel(const int* __restrict__ tok,
                             const float* __restrict__ wte,
                             float* __restrict__ x) {
    int row = blockIdx.x;
    int tid = threadIdx.x;
    int tk = tok[row];
    x[(size_t)row * CC + tid] = wte[(size_t)tk * CC + tid];
}

// ---------------------------------------------------------------------------
__global__ void cvt_kernel(const float* __restrict__ in,
                           ushort* __restrict__ out, int n4) {
    int i = blockIdx.x * 256 + threadIdx.x;
    if (i >= n4) return;
    float4 v = ((const float4*)in)[i];
    ushort4 o;
    o.x = f2bf(v.x); o.y = f2bf(v.y); o.z = f2bf(v.z); o.w = f2bf(v.w);
    ((ushort4*)out)[i] = o;
}

// ---------------------------------------------------------------------------
// LayerNorm -> bf16 output
__global__ void ln_kernel(const float* __restrict__ x,
                          const float* __restrict__ g,
                          const float* __restrict__ b,
                          ushort* __restrict__ out) {
    int row = blockIdx.x;
    int tid = threadIdx.x;
    __shared__ float r1[256];
    __shared__ float r2[256];
    float v = x[(size_t)row * CC + tid];
    r1[tid] = v;
    r2[tid] = v * v;
    __syncthreads();
    for (int off = 128; off > 0; off >>= 1) {
        if (tid < off) { r1[tid] += r1[tid + off]; r2[tid] += r2[tid + off]; }
        __syncthreads();
    }
    float mean = r1[0] * (1.0f / CC);
    float var  = r2[0] * (1.0f / CC) - mean * mean;
    float rs = rsqrtf(var + 1e-5f);
    out[(size_t)row * CC + tid] = f2bf((v - mean) * rs * g[tid] + b[tid]);
}

// ---------------------------------------------------------------------------
// bf16 MFMA GEMM: out[M,N] = A[M,K] @ W[N,K]^T (+bias)(+epilogue)
// BM=128, BN=64, BK=32, 256 threads (4 waves as 2x2), fragment-linear LDS.
// MODE: 0=store f32, 1=accumulate f32, 2=gelu->bf16, 3=qkv split->bf16
// ---------------------------------------------------------------------------
template<int MODE>
__global__ __launch_bounds__(256) void bgemm_kernel(
        const ushort* __restrict__ A,
        const ushort* __restrict__ W,
        const float* __restrict__ bias,
        float* __restrict__ out,
        ushort* __restrict__ outb,
        int N, int K,
        ushort* __restrict__ qb, ushort* __restrict__ kb,
        ushort* __restrict__ vtb) {
    __shared__ ushort lds[6144];   // A: 8 subtiles of 512, B: 4 subtiles of 512
    int tid = threadIdx.x;
    int w = tid >> 6, lane = tid & 63;
    int lo = lane & 15, hi = lane >> 4;
    int row0 = blockIdx.y * 128;
    int col0 = blockIdx.x * 64;
    int wm = w >> 1, wn = w & 1;
    f32x4 acc[4][2] = {};
    const ushort* Asrc = A + (size_t)row0 * K;
    const ushort* Wsrc = W + (size_t)col0 * K;
    int c0 = w * 2;
    for (int k0 = 0; k0 < K; k0 += 32) {
        // stage: A subtiles c0, c0+1; B subtile w. Fragment-linear layout:
        // subtile slot lane holds (row=lane%16, k=(lane/16)*8..+8) -> lds lane*16B.
        gload16(Asrc + (size_t)(c0 * 16 + lo) * K + k0 + hi * 8, &lds[c0 * 512]);
        gload16(Asrc + (size_t)(c0 * 16 + 16 + lo) * K + k0 + hi * 8, &lds[(c0 + 1) * 512]);
        gload16(Wsrc + (size_t)(w * 16 + lo) * K + k0 + hi * 8, &lds[4096 + w * 512]);
        asm volatile("s_waitcnt vmcnt(0)");
        __syncthreads();
        bf16x8 a[4], b[2];
#pragma unroll
        for (int f = 0; f < 4; ++f)
            a[f] = *(const bf16x8*)&lds[(wm * 4 + f) * 512 + lane * 8];
#pragma unroll
        for (int g = 0; g < 2; ++g)
            b[g] = *(const bf16x8*)&lds[4096 + (wn * 2 + g) * 512 + lane * 8];
#pragma unroll
        for (int f = 0; f < 4; ++f)
#pragma unroll
            for (int g = 0; g < 2; ++g)
                acc[f][g] = MFMA16(a[f], b[g], acc[f][g]);
        __syncthreads();
    }
#pragma unroll
    for (int f = 0; f < 4; ++f) {
        int rr = row0 + wm * 64 + f * 16 + hi * 4;
#pragma unroll
        for (int g = 0; g < 2; ++g) {
            int cc = col0 + wn * 32 + g * 16 + lo;
            float bv = bias ? bias[cc] : 0.0f;
#pragma unroll
            for (int j = 0; j < 4; ++j) {
                int r = rr + j;
                float v = acc[f][g][j] + bv;
                if (MODE == 3) {
                    int t = r & 2047, bb2 = r >> 11;
                    int which = cc >> 8, hh = (cc >> 6) & 3, dd = cc & 63;
                    size_t bh = (size_t)(bb2 * 4 + hh);
                    if (which == 0)      qb[(bh * 2048 + t) * 64 + dd] = f2bf(v);
                    else if (which == 1) kb[(bh * 2048 + t) * 64 + dd] = f2bf(v * 0.125f);
                    else                 vtb[(bh * 64 + dd) * 2048 + t] = f2bf(v);
                } else if (MODE == 2) {
                    outb[(size_t)r * N + cc] = f2bf(gelu_f(v));
                } else if (MODE == 1) {
                    out[(size_t)r * N + cc] += v;
                } else {
                    out[(size_t)r * N + cc] = v;
                }
            }
        }
    }
}

// ---------------------------------------------------------------------------
__global__ void emb_bf_kernel(const float* __restrict__ ek,
                              const float* __restrict__ ev,
                              ushort* __restrict__ ekp,
                              ushort* __restrict__ evtp) {
    int i = blockIdx.x * 256 + threadIdx.x;
    int rp = i >> 6, d = i & 63;
    int o = rp - 64;
    bool in = (o >= 0 && o < TT);
    float kv = in ? ek[(size_t)o * 64 + d] : 0.0f;
    float vv = in ? ev[(size_t)o * 64 + d] : 0.0f;
    ekp[(size_t)rp * 64 + d] = f2bf(kv);
    evtp[(size_t)d * EPAD + rp] = f2bf(vv);
}

// ---------------------------------------------------------------------------
// Flash attention + relative position; 4 waves/block, intra-block s-split.
// Wave w handles s-chunks it = w, w+4, ...; merge partials at the end.
// ---------------------------------------------------------------------------
__global__ __launch_bounds__(256) void flash_kernel(
        const ushort* __restrict__ qb,    // [16][2048][64]
        const ushort* __restrict__ kb,    // [16][2048][64] (pre-scaled 0.125)
        const ushort* __restrict__ vtb,   // [16][64][2048]
        const ushort* __restrict__ ekp,   // [EPAD][64]
        const ushort* __restrict__ evtp,  // [64][EPAD]
        ushort* __restrict__ y) {         // [B,T,C] bf16
    __shared__ __align__(16) char smem[4][11264];  // per-wave scratch
    __shared__ float cm[4][16];
    __shared__ float cl[4][16];

    int bid = blockIdx.x;
    int bh = bid & 15;
    int wt = 127 - (bid >> 4);            // heavy tiles first
    int t0 = wt * 16;
    int tid = threadIdx.x;
    int w = tid >> 6;
    int lane = tid & 63;
    int lo = lane & 15, hi = lane >> 4;

    float  (*Rl)[84]   = (float (*)[84])   smem[w];
    ushort (*Pl)[72]   = (ushort (*)[72]) (smem[w] + 5376);
    ushort (*Ppl)[104] = (ushort (*)[104])(smem[w] + 7680);

    const ushort* qbase = qb + ((size_t)bh * 2048 + t0) * 64;
    bf16x8 qf0 = *(const bf16x8*)(qbase + (size_t)lo * 64 + hi * 8);
    bf16x8 qf1 = *(const bf16x8*)(qbase + (size_t)lo * 64 + 32 + hi * 8);

    {   // zero own P' (valid window [r+1, r+64] is iteration-invariant)
        uint* pz = reinterpret_cast<uint*>(&Ppl[0][0]);
        for (int i = lane; i < 16 * 104 / 2; i += 64) pz[i] = 0;
    }

    float m[4], l[4];
    f32x4 O[4] = {};
#pragma unroll
    for (int j = 0; j < 4; j++) { m[j] = -1e30f; l[j] = 0.0f; }

    const ushort* vbase = vtb + (size_t)bh * 64 * 2048;
    int NS = (t0 >> 6) + 1;

    for (int it = w; it < NS; it += 4) {
        int s0 = it * 64;
        int ob = t0 - s0 - 64;

        // ---- S = Q K^T ----
        f32x4 sacc[4] = {};
        const ushort* kbb = kb + ((size_t)bh * 2048 + s0) * 64;
#pragma unroll
        for (int n = 0; n < 4; ++n) {
            bf16x8 b0 = *(const bf16x8*)(kbb + (size_t)(n * 16 + lo) * 64 + hi * 8);
            bf16x8 b1 = *(const bf16x8*)(kbb + (size_t)(n * 16 + lo) * 64 + 32 + hi * 8);
            sacc[n] = MFMA16(qf0, b0, sacc[n]);
            sacc[n] = MFMA16(qf1, b1, sacc[n]);
        }
        // ---- R = Q ek_band^T -> LDS ----
#pragma unroll
        for (int n = 0; n < 5; ++n) {
            f32x4 r = {};
            const ushort* ekr = ekp + (size_t)(64 + ob + n * 16 + lo) * 64;
            bf16x8 e0 = *(const bf16x8*)(ekr + hi * 8);
            bf16x8 e1 = *(const bf16x8*)(ekr + 32 + hi * 8);
            r = MFMA16(qf0, e0, r);
            r = MFMA16(qf1, e1, r);
#pragma unroll
            for (int j = 0; j < 4; ++j) Rl[hi * 4 + j][n * 16 + lo] = r[j];
        }
        // ---- combine + mask + online softmax ----
        float sv[4][4];
        float mrow[4] = {-1e30f, -1e30f, -1e30f, -1e30f};
#pragma unroll
        for (int n = 0; n < 4; ++n) {
            int sl = n * 16 + lo;
#pragma unroll
            for (int j = 0; j < 4; ++j) {
                int r_ = hi * 4 + j;
                float v = sacc[n][j] + Rl[r_][r_ - sl + 64];
                v = (s0 + sl <= t0 + r_) ? v : -1e30f;
                sv[n][j] = v;
                mrow[j] = fmaxf(mrow[j], v);
            }
        }
#pragma unroll
        for (int msk = 1; msk < 16; msk <<= 1)
#pragma unroll
            for (int j = 0; j < 4; ++j)
                mrow[j] = fmaxf(mrow[j], __shfl_xor(mrow[j], msk));
        float alpha[4];
#pragma unroll
        for (int j = 0; j < 4; ++j) {
            float mn = fmaxf(m[j], mrow[j]);
            alpha[j] = __expf(m[j] - mn);
            m[j] = mn;
        }
        float rs[4] = {0, 0, 0, 0};
#pragma unroll
        for (int n = 0; n < 4; ++n) {
            int sl = n * 16 + lo;
#pragma unroll
            for (int j = 0; j < 4; ++j) {
                int r_ = hi * 4 + j;
                float p = __expf(sv[n][j] - m[j]);
                rs[j] += p;
                ushort pu = f2bf(p);
                Pl[r_][sl] = pu;
                Ppl[r_][r_ - sl + 64] = pu;
            }
        }
#pragma unroll
        for (int msk = 1; msk < 16; msk <<= 1)
#pragma unroll
            for (int j = 0; j < 4; ++j) rs[j] += __shfl_xor(rs[j], msk);
#pragma unroll
        for (int j = 0; j < 4; ++j) l[j] = l[j] * alpha[j] + rs[j];
#pragma unroll
        for (int n = 0; n < 4; ++n)
#pragma unroll
            for (int j = 0; j < 4; ++j) O[n][j] *= alpha[j];

        // ---- O += P V + P' embv_band ----
#pragma unroll
        for (int n = 0; n < 4; ++n) {
            const ushort* vr = vbase + (size_t)(n * 16 + lo) * 2048;
            const ushort* er = evtp + (size_t)(n * 16 + lo) * EPAD + 64 + ob;
#pragma unroll
            for (int kc = 0; kc < 2; ++kc) {
                bf16x8 a = *(const bf16x8*)(&Pl[lo][kc * 32 + hi * 8]);
                bf16x8 b = *(const bf16x8*)(vr + s0 + kc * 32 + hi * 8);
                O[n] = MFMA16(a, b, O[n]);
            }
#pragma unroll
            for (int kc = 0; kc < 3; ++kc) {
                bf16x8 a = *(const bf16x8*)(&Ppl[lo][kc * 32 + hi * 8]);
                bf16x8 b = *(const bf16x8*)(er + kc * 32 + hi * 8);
                O[n] = MFMA16(a, b, O[n]);
            }
        }
    }

    // ---- write partials: O tile into own region, (m,l) into cm/cl ----
    float* Of = (float*)smem[w];
#pragma unroll
    for (int n = 0; n < 4; ++n)
#pragma unroll
        for (int j = 0; j < 4; ++j)
            Of[(hi * 4 + j) * 64 + n * 16 + lo] = O[n][j];
    if (lo == 0) {
#pragma unroll
        for (int j = 0; j < 4; ++j) {
            cm[w][hi * 4 + j] = m[j];
            cl[w][hi * 4 + j] = l[j];
        }
    }
    __syncthreads();

    // ---- merge 4 partials; wave w owns output col block w*16 ----
    int b_ = bh >> 2, h_ = bh & 3;
#pragma unroll
    for (int j = 0; j < 4; ++j) {
        int r = hi * 4 + j;
        float M0 = fmaxf(fmaxf(cm[0][r], cm[1][r]), fmaxf(cm[2][r], cm[3][r]));
        float den = 0.0f, num = 0.0f;
#pragma unroll
        for (int ww = 0; ww < 4; ++ww) {
            float sc_ = __expf(cm[ww][r] - M0);
            den += sc_ * cl[ww][r];
            num += sc_ * ((float*)smem[ww])[r * 64 + w * 16 + lo];
        }
        y[((size_t)(b_ * 2048 + t0 + r)) * 256 + h_ * 64 + w * 16 + lo] =
            f2bf(num / den);
    }
}

// ---------------------------------------------------------------------------
extern "C" void kernel_launch(void* const* d_in, const int* in_sizes, int n_in,
                              void* d_out, int out_size, void* d_ws, size_t ws_size,
                              hipStream_t stream) {
    const int*   tokens  = (const int*)d_in[0];
    const float* wte     = (const float*)d_in[1];
    const float* ln1_g   = (const float*)d_in[2];
    const float* ln1_b   = (const float*)d_in[3];
    const float* attn_w  = (const float*)d_in[4];
    const float* attn_b  = (const float*)d_in[5];
    const float* proj_w  = (const float*)d_in[6];
    const float* proj_b  = (const float*)d_in[7];
    const float* embk    = (const float*)d_in[8];
    const float* embv    = (const float*)d_in[9];
    const float* ln2_g   = (const float*)d_in[10];
    const float* ln2_b   = (const float*)d_in[11];
    const float* fc_w    = (const float*)d_in[12];
    const float* fc_b    = (const float*)d_in[13];
    const float* mproj_w = (const float*)d_in[14];
    const float* mproj_b = (const float*)d_in[15];
    const float* lnf_g   = (const float*)d_in[16];
    const float* lnf_b   = (const float*)d_in[17];
    const float* head_w  = (const float*)d_in[18];
    float* out = (float*)d_out;

    const int M = BB * TT;  // 8192
    char* wsb = (char*)d_ws;
    float*  x    = (float*)wsb;                               // 8 MB
    ushort* h    = (ushort*)(wsb + ((size_t)8 << 20));        // 4 MB
    ushort* y    = (ushort*)(wsb + ((size_t)12 << 20));       // 4 MB
    ushort* qb   = (ushort*)(wsb + ((size_t)16 << 20));       // 4 MB
    ushort* kbf  = (ushort*)(wsb + ((size_t)20 << 20));       // 4 MB
    ushort* vtb  = (ushort*)(wsb + ((size_t)24 << 20));       // 4 MB
    ushort* ekp  = (ushort*)(wsb + ((size_t)28 << 20));       // 278 KB
    ushort* evtp = (ushort*)(wsb + ((size_t)28 << 20) + 524288);
    ushort* wcvt = (ushort*)(wsb + ((size_t)29 << 20));       // 3.7 MB
    ushort* attn_wb  = wcvt;
    ushort* proj_wb  = attn_wb + (size_t)LL * 3 * CC * CC;
    ushort* fc_wb    = proj_wb + (size_t)LL * CC * CC;
    ushort* mproj_wb = fc_wb + (size_t)LL * 4 * CC * CC;
    ushort* head_wb  = mproj_wb + (size_t)LL * CC * 4 * CC;
    ushort* fcb = (ushort*)d_out;  // d_out reused as fc scratch (bf16)

    dim3 blk(256);

    // weight conversions (each n divisible by 1024)
    cvt_kernel<<<dim3(LL * 3 * CC * CC / 1024), blk, 0, stream>>>(attn_w, attn_wb, LL * 3 * CC * CC / 4);
    cvt_kernel<<<dim3(LL * CC * CC / 1024), blk, 0, stream>>>(proj_w, proj_wb, LL * CC * CC / 4);
    cvt_kernel<<<dim3(LL * 4 * CC * CC / 1024), blk, 0, stream>>>(fc_w, fc_wb, LL * 4 * CC * CC / 4);
    cvt_kernel<<<dim3(LL * CC * 4 * CC / 1024), blk, 0, stream>>>(mproj_w, mproj_wb, LL * CC * 4 * CC / 4);
    cvt_kernel<<<dim3(VV * CC / 1024), blk, 0, stream>>>(head_w, head_wb, VV * CC / 4);

    embed_kernel<<<dim3(M), blk, 0, stream>>>(tokens, wte, x);

    for (int l = 0; l < LL; l++) {
        ln_kernel<<<dim3(M), blk, 0, stream>>>(x, ln1_g + l * CC, ln1_b + l * CC, h);
        bgemm_kernel<3><<<dim3(12, 64), blk, 0, stream>>>(
            h, attn_wb + (size_t)l * 3 * CC * CC, attn_b + (size_t)l * 3 * CC,
            nullptr, nullptr, 3 * CC, CC, qb, kbf, vtb);
        emb_bf_kernel<<<dim3(EPAD * 64 / 256), blk, 0, stream>>>(
            embk + (size_t)l * TT * HS, embv + (size_t)l * TT * HS, ekp, evtp);
        flash_kernel<<<dim3(2048), blk, 0, stream>>>(qb, kbf, vtb, ekp, evtp, y);
        bgemm_kernel<1><<<dim3(4, 64), blk, 0, stream>>>(
            y, proj_wb + (size_t)l * CC * CC, proj_b + (size_t)l * CC,
            x, nullptr, CC, CC, nullptr, nullptr, nullptr);
        ln_kernel<<<dim3(M), blk, 0, stream>>>(x, ln2_g + l * CC, ln2_b + l * CC, h);
        bgemm_kernel<2><<<dim3(16, 64), blk, 0, stream>>>(
            h, fc_wb + (size_t)l * 4 * CC * CC, fc_b + (size_t)l * 4 * CC,
            nullptr, fcb, 4 * CC, CC, nullptr, nullptr, nullptr);
        bgemm_kernel<1><<<dim3(4, 64), blk, 0, stream>>>(
            fcb, mproj_wb + (size_t)l * CC * 4 * CC, mproj_b + (size_t)l * CC,
            x, nullptr, CC, 4 * CC, nullptr, nullptr, nullptr);
    }

    ln_kernel<<<dim3(M), blk, 0, stream>>>(x, lnf_g, lnf_b, h);
    bgemm_kernel<0><<<dim3(16, 64), blk, 0, stream>>>(
        h, head_wb, nullptr, out, nullptr, VV, CC, nullptr, nullptr, nullptr);
}

// Round 4
// 510.357 us; speedup vs baseline: 12.9978x; 1.0895x over previous
//
#include <hip/hip_runtime.h>
#include <hip/hip_bf16.h>
#include <math.h>

#define BB 4
#define TT 2048
#define CC 256
#define HH 4
#define LL 2
#define VV 1024
#define HS 64
#define EPAD 2176

typedef __attribute__((ext_vector_type(8))) __bf16 bf16x8;
typedef __attribute__((ext_vector_type(4))) float f32x4;

#define MFMA16(a, b, c) __builtin_amdgcn_mfma_f32_16x16x32_bf16((a), (b), (c), 0, 0, 0)

__device__ __forceinline__ ushort f2bf(float f) {
    __hip_bfloat16 h = __float2bfloat16(f);
    return *reinterpret_cast<ushort*>(&h);
}

__device__ __forceinline__ void gload16(const void* g, void* l) {
    __builtin_amdgcn_global_load_lds(
        (const __attribute__((address_space(1))) void*)g,
        (__attribute__((address_space(3))) void*)l, 16, 0, 0);
}

__device__ __forceinline__ float gelu_f(float v) {
    return 0.5f * v * (1.0f + tanhf(0.7978845608028654f * (v + 0.044715f * v * v * v)));
}

// ---------------------------------------------------------------------------
__global__ void embed_kernel(const int* __restrict__ tok,
                             const float* __restrict__ wte,
                             float* __restrict__ x) {
    int row = blockIdx.x;
    int tid = threadIdx.x;
    int tk = tok[row];
    x[(size_t)row * CC + tid] = wte[(size_t)tk * CC + tid];
}

// ---------------------------------------------------------------------------
// All 5 weight tensors -> bf16 in one launch. Sizes are compile-time.
// float4 index prefix sums: 98304, 131072, 262144, 393216, 458752
// ---------------------------------------------------------------------------
__global__ void cvt5_kernel(const float* __restrict__ w0, const float* __restrict__ w1,
                            const float* __restrict__ w2, const float* __restrict__ w3,
                            const float* __restrict__ w4,
                            ushort* __restrict__ o0, ushort* __restrict__ o1,
                            ushort* __restrict__ o2, ushort* __restrict__ o3,
                            ushort* __restrict__ o4) {
    int i = blockIdx.x * 256 + threadIdx.x;
    const float* src; ushort* dst; int j;
    if (i < 98304)       { src = w0; dst = o0; j = i; }
    else if (i < 131072) { src = w1; dst = o1; j = i - 98304; }
    else if (i < 262144) { src = w2; dst = o2; j = i - 131072; }
    else if (i < 393216) { src = w3; dst = o3; j = i - 262144; }
    else                 { src = w4; dst = o4; j = i - 393216; }
    float4 v = ((const float4*)src)[j];
    ushort4 o;
    o.x = f2bf(v.x); o.y = f2bf(v.y); o.z = f2bf(v.z); o.w = f2bf(v.w);
    ((ushort4*)dst)[j] = o;
}

// ---------------------------------------------------------------------------
// LayerNorm -> bf16, one wave per row, no barriers.
// ---------------------------------------------------------------------------
__global__ __launch_bounds__(256) void ln_kernel(const float* __restrict__ x,
                                                 const float* __restrict__ g,
                                                 const float* __restrict__ b,
                                                 ushort* __restrict__ out) {
    int row = blockIdx.x * 4 + (threadIdx.x >> 6);
    int lane = threadIdx.x & 63;
    float4 v = ((const float4*)(x + (size_t)row * CC))[lane];
    float s = v.x + v.y + v.z + v.w;
    float s2 = v.x * v.x + v.y * v.y + v.z * v.z + v.w * v.w;
    for (int m = 1; m < 64; m <<= 1) {
        s += __shfl_xor(s, m);
        s2 += __shfl_xor(s2, m);
    }
    float mean = s * (1.0f / CC);
    float var = s2 * (1.0f / CC) - mean * mean;
    float rs = rsqrtf(var + 1e-5f);
    float4 gg = ((const float4*)g)[lane];
    float4 bb = ((const float4*)b)[lane];
    ushort4 o;
    o.x = f2bf((v.x - mean) * rs * gg.x + bb.x);
    o.y = f2bf((v.y - mean) * rs * gg.y + bb.y);
    o.z = f2bf((v.z - mean) * rs * gg.z + bb.z);
    o.w = f2bf((v.w - mean) * rs * gg.w + bb.w);
    ((ushort4*)(out + (size_t)row * CC))[lane] = o;
}

// ---------------------------------------------------------------------------
// bf16 MFMA GEMM, BM=128 x BN=64, BK=32, 4 waves (2x2), double-buffered LDS.
// MODE: 0=store f32, 2=gelu->bf16, 3=qkv split->bf16
// ---------------------------------------------------------------------------
template<int MODE>
__global__ __launch_bounds__(256) void bgemm128_kernel(
        const ushort* __restrict__ A, const ushort* __restrict__ W,
        const float* __restrict__ bias, float* __restrict__ out,
        ushort* __restrict__ outb, int N, int K,
        ushort* __restrict__ qb, ushort* __restrict__ kb,
        ushort* __restrict__ vtb) {
    constexpr int ASUB = 8, TOT = 12, BUFSH = 192 * 32;  // 6144 ushorts = 12 KB
    __shared__ ushort lds[2 * BUFSH];
    int tid = threadIdx.x;
    int w = tid >> 6, lane = tid & 63;
    int lo = lane & 15, hi = lane >> 4;
    int row0 = blockIdx.y * 128;
    int col0 = blockIdx.x * 64;
    int wm = w >> 1, wn = w & 1;
    const ushort* Asrc = A + (size_t)row0 * K;
    const ushort* Wsrc = W + (size_t)col0 * K;

    auto STAGE = [&](int buf, int k0) {
        ushort* dst = &lds[buf * BUFSH];
        for (int s = w; s < TOT; s += 4) {
            const ushort* src;
            if (s < ASUB) src = Asrc + (size_t)(s * 16 + lo) * K + k0 + hi * 8;
            else          src = Wsrc + (size_t)((s - ASUB) * 16 + lo) * K + k0 + hi * 8;
            gload16(src, dst + s * 512);
        }
    };

    f32x4 acc[4][2] = {};
    int NT = K >> 5;
    STAGE(0, 0);
    asm volatile("s_waitcnt vmcnt(0)" ::: "memory");
    __syncthreads();
    for (int t = 0; t < NT; ++t) {
        int buf = t & 1;
        if (t + 1 < NT) STAGE(buf ^ 1, (t + 1) << 5);
        bf16x8 a[4], b[2];
#pragma unroll
        for (int f = 0; f < 4; ++f)
            a[f] = *(const bf16x8*)&lds[buf * BUFSH + (wm * 4 + f) * 512 + lane * 8];
#pragma unroll
        for (int g = 0; g < 2; ++g)
            b[g] = *(const bf16x8*)&lds[buf * BUFSH + (ASUB + wn * 2 + g) * 512 + lane * 8];
        __builtin_amdgcn_s_setprio(1);
#pragma unroll
        for (int f = 0; f < 4; ++f)
#pragma unroll
            for (int g = 0; g < 2; ++g)
                acc[f][g] = MFMA16(a[f], b[g], acc[f][g]);
        __builtin_amdgcn_s_setprio(0);
        asm volatile("s_waitcnt vmcnt(0)" ::: "memory");
        __syncthreads();
    }
#pragma unroll
    for (int f = 0; f < 4; ++f) {
        int rr = row0 + wm * 64 + f * 16 + hi * 4;
#pragma unroll
        for (int g = 0; g < 2; ++g) {
            int cc = col0 + wn * 32 + g * 16 + lo;
            float bv = bias ? bias[cc] : 0.0f;
#pragma unroll
            for (int j = 0; j < 4; ++j) {
                int r = rr + j;
                float v = acc[f][g][j] + bv;
                if (MODE == 3) {
                    int t = r & 2047, bb2 = r >> 11;
                    int which = cc >> 8, hh = (cc >> 6) & 3, dd = cc & 63;
                    size_t bh = (size_t)(bb2 * 4 + hh);
                    if (which == 0)      qb[(bh * 2048 + t) * 64 + dd] = f2bf(v);
                    else if (which == 1) kb[(bh * 2048 + t) * 64 + dd] = f2bf(v * 0.125f);
                    else                 vtb[(bh * 64 + dd) * 2048 + t] = f2bf(v);
                } else if (MODE == 2) {
                    outb[(size_t)r * N + cc] = f2bf(gelu_f(v));
                } else {
                    out[(size_t)r * N + cc] = v;
                }
            }
        }
    }
}

// ---------------------------------------------------------------------------
// bf16 MFMA GEMM, BM=64 x BN=64, BK=64, 4 waves (1 row-strip each),
// double-buffered. MODE 1 only: accumulate f32 (+bias).
// ---------------------------------------------------------------------------
__global__ __launch_bounds__(256) void bgemm64_kernel(
        const ushort* __restrict__ A, const ushort* __restrict__ W,
        const float* __restrict__ bias, float* __restrict__ out,
        int N, int K) {
    constexpr int ASUB = 8, TOT = 16, BUFSH = 128 * 64;  // 8192 ushorts = 16 KB
    __shared__ ushort lds[2 * BUFSH];
    int tid = threadIdx.x;
    int w = tid >> 6, lane = tid & 63;
    int lo = lane & 15, hi = lane >> 4;
    int row0 = blockIdx.y * 64;
    int col0 = blockIdx.x * 64;
    const ushort* Asrc = A + (size_t)row0 * K;
    const ushort* Wsrc = W + (size_t)col0 * K;

    auto STAGE = [&](int buf, int k0) {
        ushort* dst = &lds[buf * BUFSH];
        for (int s = w; s < TOT; s += 4) {
            const ushort* src;
            if (s < ASUB) {
                int rg = s >> 1, kh = s & 1;
                src = Asrc + (size_t)(rg * 16 + lo) * K + k0 + kh * 32 + hi * 8;
            } else {
                int s2 = s - ASUB;
                int cg = s2 >> 1, kh = s2 & 1;
                src = Wsrc + (size_t)(cg * 16 + lo) * K + k0 + kh * 32 + hi * 8;
            }
            gload16(src, dst + s * 512);
        }
    };

    f32x4 acc[4] = {};
    int NT = K >> 6;
    STAGE(0, 0);
    asm volatile("s_waitcnt vmcnt(0)" ::: "memory");
    __syncthreads();
    for (int t = 0; t < NT; ++t) {
        int buf = t & 1;
        if (t + 1 < NT) STAGE(buf ^ 1, (t + 1) << 6);
        bf16x8 a[2];
#pragma unroll
        for (int kh = 0; kh < 2; ++kh)
            a[kh] = *(const bf16x8*)&lds[buf * BUFSH + (w * 2 + kh) * 512 + lane * 8];
        __builtin_amdgcn_s_setprio(1);
#pragma unroll
        for (int g = 0; g < 4; ++g) {
#pragma unroll
            for (int kh = 0; kh < 2; ++kh) {
                bf16x8 b = *(const bf16x8*)&lds[buf * BUFSH + (ASUB + g * 2 + kh) * 512 + lane * 8];
                acc[g] = MFMA16(a[kh], b, acc[g]);
            }
        }
        __builtin_amdgcn_s_setprio(0);
        asm volatile("s_waitcnt vmcnt(0)" ::: "memory");
        __syncthreads();
    }
#pragma unroll
    for (int g = 0; g < 4; ++g) {
        int cc = col0 + g * 16 + lo;
        float bv = bias ? bias[cc] : 0.0f;
#pragma unroll
        for (int j = 0; j < 4; ++j) {
            int r = row0 + w * 16 + hi * 4 + j;
            out[(size_t)r * N + cc] += acc[g][j] + bv;
        }
    }
}

// ---------------------------------------------------------------------------
__global__ void emb_bf_kernel(const float* __restrict__ ek,
                              const float* __restrict__ ev,
                              ushort* __restrict__ ekp,
                              ushort* __restrict__ evtp) {
    int i = blockIdx.x * 256 + threadIdx.x;
    int rp = i >> 6, d = i & 63;
    int o = rp - 64;
    bool in = (o >= 0 && o < TT);
    float kv = in ? ek[(size_t)o * 64 + d] : 0.0f;
    float vv = in ? ev[(size_t)o * 64 + d] : 0.0f;
    ekp[(size_t)rp * 64 + d] = f2bf(kv);
    evtp[(size_t)d * EPAD + rp] = f2bf(vv);
}

// ---------------------------------------------------------------------------
// Flash attention + relative position; 4 waves/block (intra-block s-split).
// Per-wave LDS region 8704 B: Rl[16][84] f32 (0..5375, aliased by Pl[16][72]
// ushort and the final O-partial), Ppl[16][104] ushort at 5376 (persistent
// zero halo). Same-wave DS ordering makes the alias safe; asm memory fences
// stop compiler reordering across the alias.
// ---------------------------------------------------------------------------
__global__ __launch_bounds__(256) void flash_kernel(
        const ushort* __restrict__ qb,    // [16][2048][64]
        const ushort* __restrict__ kb,    // [16][2048][64] (pre-scaled 0.125)
        const ushort* __restrict__ vtb,   // [16][64][2048]
        const ushort* __restrict__ ekp,   // [EPAD][64]
        const ushort* __restrict__ evtp,  // [64][EPAD]
        ushort* __restrict__ y) {         // [B,T,C] bf16
    __shared__ __align__(16) char smem[4][8704];
    __shared__ float cm[4][16];
    __shared__ float cl[4][16];

    int bid = blockIdx.x;
    int bh = bid & 15;
    int wt = 127 - (bid >> 4);            // heavy tiles first
    int t0 = wt * 16;
    int tid = threadIdx.x;
    int w = tid >> 6;
    int lane = tid & 63;
    int lo = lane & 15, hi = lane >> 4;

    float  (*Rl)[84]   = (float (*)[84])   smem[w];
    ushort (*Pl)[72]   = (ushort (*)[72])  smem[w];          // aliases Rl
    ushort (*Ppl)[104] = (ushort (*)[104])(smem[w] + 5376);

    const ushort* qbase = qb + ((size_t)bh * 2048 + t0) * 64;
    bf16x8 qf0 = *(const bf16x8*)(qbase + (size_t)lo * 64 + hi * 8);
    bf16x8 qf1 = *(const bf16x8*)(qbase + (size_t)lo * 64 + 32 + hi * 8);

    {   // zero own P' (valid window [r+1, r+64] is iteration-invariant)
        uint* pz = reinterpret_cast<uint*>(&Ppl[0][0]);
        for (int i = lane; i < 16 * 104 / 2; i += 64) pz[i] = 0;
    }

    float m[4], l[4];
    f32x4 O[4] = {};
#pragma unroll
    for (int j = 0; j < 4; j++) { m[j] = -1e30f; l[j] = 0.0f; }

    const ushort* vbase = vtb + (size_t)bh * 64 * 2048;
    int NS = (t0 >> 6) + 1;

    for (int it = w; it < NS; it += 4) {
        int s0 = it * 64;
        int ob = t0 - s0 - 64;

        // ---- S = Q K^T ----
        f32x4 sacc[4] = {};
        const ushort* kbb = kb + ((size_t)bh * 2048 + s0) * 64;
        __builtin_amdgcn_s_setprio(1);
#pragma unroll
        for (int n = 0; n < 4; ++n) {
            bf16x8 b0 = *(const bf16x8*)(kbb + (size_t)(n * 16 + lo) * 64 + hi * 8);
            bf16x8 b1 = *(const bf16x8*)(kbb + (size_t)(n * 16 + lo) * 64 + 32 + hi * 8);
            sacc[n] = MFMA16(qf0, b0, sacc[n]);
            sacc[n] = MFMA16(qf1, b1, sacc[n]);
        }
        // ---- R = Q ek_band^T -> LDS ----
#pragma unroll
        for (int n = 0; n < 5; ++n) {
            f32x4 r = {};
            const ushort* ekr = ekp + (size_t)(64 + ob + n * 16 + lo) * 64;
            bf16x8 e0 = *(const bf16x8*)(ekr + hi * 8);
            bf16x8 e1 = *(const bf16x8*)(ekr + 32 + hi * 8);
            r = MFMA16(qf0, e0, r);
            r = MFMA16(qf1, e1, r);
#pragma unroll
            for (int j = 0; j < 4; ++j) Rl[hi * 4 + j][n * 16 + lo] = r[j];
        }
        __builtin_amdgcn_s_setprio(0);
        // ---- combine + mask + online softmax (reads Rl) ----
        float sv[4][4];
        float mrow[4] = {-1e30f, -1e30f, -1e30f, -1e30f};
#pragma unroll
        for (int n = 0; n < 4; ++n) {
            int sl = n * 16 + lo;
#pragma unroll
            for (int j = 0; j < 4; ++j) {
                int r_ = hi * 4 + j;
                float v = sacc[n][j] + Rl[r_][r_ - sl + 64];
                v = (s0 + sl <= t0 + r_) ? v : -1e30f;
                sv[n][j] = v;
                mrow[j] = fmaxf(mrow[j], v);
            }
        }
        asm volatile("" ::: "memory");   // Rl reads before Pl writes (alias)
#pragma unroll
        for (int msk = 1; msk < 16; msk <<= 1)
#pragma unroll
            for (int j = 0; j < 4; ++j)
                mrow[j] = fmaxf(mrow[j], __shfl_xor(mrow[j], msk));
        float alpha[4];
#pragma unroll
        for (int j = 0; j < 4; ++j) {
            float mn = fmaxf(m[j], mrow[j]);
            alpha[j] = __expf(m[j] - mn);
            m[j] = mn;
        }
        float rs[4] = {0, 0, 0, 0};
#pragma unroll
        for (int n = 0; n < 4; ++n) {
            int sl = n * 16 + lo;
#pragma unroll
            for (int j = 0; j < 4; ++j) {
                int r_ = hi * 4 + j;
                float p = __expf(sv[n][j] - m[j]);
                rs[j] += p;
                ushort pu = f2bf(p);
                Pl[r_][sl] = pu;
                Ppl[r_][r_ - sl + 64] = pu;
            }
        }
#pragma unroll
        for (int msk = 1; msk < 16; msk <<= 1)
#pragma unroll
            for (int j = 0; j < 4; ++j) rs[j] += __shfl_xor(rs[j], msk);
#pragma unroll
        for (int j = 0; j < 4; ++j) l[j] = l[j] * alpha[j] + rs[j];
#pragma unroll
        for (int n = 0; n < 4; ++n)
#pragma unroll
            for (int j = 0; j < 4; ++j) O[n][j] *= alpha[j];

        // ---- O += P V + P' embv_band ----
        __builtin_amdgcn_s_setprio(1);
#pragma unroll
        for (int n = 0; n < 4; ++n) {
            const ushort* vr = vbase + (size_t)(n * 16 + lo) * 2048;
            const ushort* er = evtp + (size_t)(n * 16 + lo) * EPAD + 64 + ob;
#pragma unroll
            for (int kc = 0; kc < 2; ++kc) {
                bf16x8 a = *(const bf16x8*)(&Pl[lo][kc * 32 + hi * 8]);
                bf16x8 b = *(const bf16x8*)(vr + s0 + kc * 32 + hi * 8);
                O[n] = MFMA16(a, b, O[n]);
            }
#pragma unroll
            for (int kc = 0; kc < 3; ++kc) {
                bf16x8 a = *(const bf16x8*)(&Ppl[lo][kc * 32 + hi * 8]);
                bf16x8 b = *(const bf16x8*)(er + kc * 32 + hi * 8);
                O[n] = MFMA16(a, b, O[n]);
            }
        }
        __builtin_amdgcn_s_setprio(0);
        asm volatile("" ::: "memory");   // Pl reads before next iter's Rl writes
    }

    // ---- write partials (O aliases Rl/Pl region; loop is done) ----
    float* Of = (float*)smem[w];
#pragma unroll
    for (int n = 0; n < 4; ++n)
#pragma unroll
        for (int j = 0; j < 4; ++j)
            Of[(hi * 4 + j) * 64 + n * 16 + lo] = O[n][j];
    if (lo == 0) {
#pragma unroll
        for (int j = 0; j < 4; ++j) {
            cm[w][hi * 4 + j] = m[j];
            cl[w][hi * 4 + j] = l[j];
        }
    }
    __syncthreads();

    int b_ = bh >> 2, h_ = bh & 3;
#pragma unroll
    for (int j = 0; j < 4; ++j) {
        int r = hi * 4 + j;
        float M0 = fmaxf(fmaxf(cm[0][r], cm[1][r]), fmaxf(cm[2][r], cm[3][r]));
        float den = 0.0f, num = 0.0f;
#pragma unroll
        for (int ww = 0; ww < 4; ++ww) {
            float sc_ = __expf(cm[ww][r] - M0);
            den += sc_ * cl[ww][r];
            num += sc_ * ((float*)smem[ww])[r * 64 + w * 16 + lo];
        }
        y[((size_t)(b_ * 2048 + t0 + r)) * 256 + h_ * 64 + w * 16 + lo] =
            f2bf(num / den);
    }
}

// ---------------------------------------------------------------------------
extern "C" void kernel_launch(void* const* d_in, const int* in_sizes, int n_in,
                              void* d_out, int out_size, void* d_ws, size_t ws_size,
                              hipStream_t stream) {
    const int*   tokens  = (const int*)d_in[0];
    const float* wte     = (const float*)d_in[1];
    const float* ln1_g   = (const float*)d_in[2];
    const float* ln1_b   = (const float*)d_in[3];
    const float* attn_w  = (const float*)d_in[4];
    const float* attn_b  = (const float*)d_in[5];
    const float* proj_w  = (const float*)d_in[6];
    const float* proj_b  = (const float*)d_in[7];
    const float* embk    = (const float*)d_in[8];
    const float* embv    = (const float*)d_in[9];
    const float* ln2_g   = (const float*)d_in[10];
    const float* ln2_b   = (const float*)d_in[11];
    const float* fc_w    = (const float*)d_in[12];
    const float* fc_b    = (const float*)d_in[13];
    const float* mproj_w = (const float*)d_in[14];
    const float* mproj_b = (const float*)d_in[15];
    const float* lnf_g   = (const float*)d_in[16];
    const float* lnf_b   = (const float*)d_in[17];
    const float* head_w  = (const float*)d_in[18];
    float* out = (float*)d_out;

    const int M = BB * TT;  // 8192
    char* wsb = (char*)d_ws;
    float*  x    = (float*)wsb;                               // 8 MB
    ushort* h    = (ushort*)(wsb + ((size_t)8 << 20));        // 4 MB
    ushort* y    = (ushort*)(wsb + ((size_t)12 << 20));       // 4 MB
    ushort* qb   = (ushort*)(wsb + ((size_t)16 << 20));       // 4 MB
    ushort* kbf  = (ushort*)(wsb + ((size_t)20 << 20));       // 4 MB
    ushort* vtb  = (ushort*)(wsb + ((size_t)24 << 20));       // 4 MB
    ushort* ekp  = (ushort*)(wsb + ((size_t)28 << 20));
    ushort* evtp = (ushort*)(wsb + ((size_t)28 << 20) + 524288);
    ushort* attn_wb  = (ushort*)(wsb + ((size_t)29 << 20));   // 3.7 MB total
    ushort* proj_wb  = attn_wb + (size_t)LL * 3 * CC * CC;
    ushort* fc_wb    = proj_wb + (size_t)LL * CC * CC;
    ushort* mproj_wb = fc_wb + (size_t)LL * 4 * CC * CC;
    ushort* head_wb  = mproj_wb + (size_t)LL * CC * 4 * CC;
    ushort* fcb = (ushort*)d_out;  // d_out reused as fc scratch (bf16)

    dim3 blk(256);

    cvt5_kernel<<<dim3(1792), blk, 0, stream>>>(
        attn_w, proj_w, fc_w, mproj_w, head_w,
        attn_wb, proj_wb, fc_wb, mproj_wb, head_wb);

    embed_kernel<<<dim3(M), blk, 0, stream>>>(tokens, wte, x);

    for (int l = 0; l < LL; l++) {
        ln_kernel<<<dim3(M / 4), blk, 0, stream>>>(x, ln1_g + l * CC, ln1_b + l * CC, h);
        bgemm128_kernel<3><<<dim3(12, 64), blk, 0, stream>>>(
            h, attn_wb + (size_t)l * 3 * CC * CC, attn_b + (size_t)l * 3 * CC,
            nullptr, nullptr, 3 * CC, CC, qb, kbf, vtb);
        emb_bf_kernel<<<dim3(EPAD * 64 / 256), blk, 0, stream>>>(
            embk + (size_t)l * TT * HS, embv + (size_t)l * TT * HS, ekp, evtp);
        flash_kernel<<<dim3(2048), blk, 0, stream>>>(qb, kbf, vtb, ekp, evtp, y);
        bgemm64_kernel<<<dim3(4, 128), blk, 0, stream>>>(
            y, proj_wb + (size_t)l * CC * CC, proj_b + (size_t)l * CC,
            x, CC, CC);
        ln_kernel<<<dim3(M / 4), blk, 0, stream>>>(x, ln2_g + l * CC, ln2_b + l * CC, h);
        bgemm128_kernel<2><<<dim3(16, 64), blk, 0, stream>>>(
            h, fc_wb + (size_t)l * 4 * CC * CC, fc_b + (size_t)l * 4 * CC,
            nullptr, fcb, 4 * CC, CC, nullptr, nullptr, nullptr);
        bgemm64_kernel<<<dim3(4, 128), blk, 0, stream>>>(
            fcb, mproj_wb + (size_t)l * CC * 4 * CC, mproj_b + (size_t)l * CC,
            x, CC, 4 * CC);
    }

    ln_kernel<<<dim3(M / 4), blk, 0, stream>>>(x, lnf_g, lnf_b, h);
    bgemm128_kernel<0><<<dim3(16, 64), blk, 0, stream>>>(
        h, head_wb, nullptr, out, nullptr, VV, CC, nullptr, nullptr, nullptr);
}